// Round 5
// baseline (285.903 us; speedup 1.0000x reference)
//
#include <hip/hip_runtime.h>
#include <math.h>

#define BATCH 4
#define TSEQ  2048
#define CEMB  1024
#define NHEAD 16
#define HD    64
#define MROWS (BATCH * TSEQ)   // 8192
#define QSCALE 11.5415603271f  // 8 * log2(e): softmax runs in exp2 domain

typedef _Float16 half8 __attribute__((ext_vector_type(8)));
typedef _Float16 half4 __attribute__((ext_vector_type(4)));
typedef _Float16 half2 __attribute__((ext_vector_type(2)));
typedef float    floatx4 __attribute__((ext_vector_type(4)));

#define GLOBAL_AS __attribute__((address_space(1)))
#define LDS_AS    __attribute__((address_space(3)))

__device__ __forceinline__ void lds_dma16(const _Float16* g, _Float16* l) {
    __builtin_amdgcn_global_load_lds((const GLOBAL_AS unsigned int*)g,
                                     (LDS_AS unsigned int*)l, 16, 0, 0);
}

// raw v_exp_f32 (2^x). VALU interlocks handle the hazard; exp2(-inf)=0.
__device__ __forceinline__ float fast_exp2(float x) {
    float r; asm("v_exp_f32 %0, %1" : "=v"(r) : "v"(x)); return r;
}

// packed f32->f16 conversion: 2 v_cvt_pkrtz instead of ~6 cvt+pack ops.
// builtin returns __fp16x2; bit_cast to our _Float16-based half2.
__device__ __forceinline__ half4 pack4(float a0, float a1, float a2, float a3) {
    half2 lo = __builtin_bit_cast(half2, __builtin_amdgcn_cvt_pkrtz(a0, a1));
    half2 hi = __builtin_bit_cast(half2, __builtin_amdgcn_cvt_pkrtz(a2, a3));
    return (half4){lo[0], lo[1], hi[0], hi[1]};
}

// ---------------------------------------------------------------------------
// Kernel 0: fp32 -> fp16 convert prepass (float4 -> half4)
// ---------------------------------------------------------------------------
__global__ __launch_bounds__(256)
void cvt_fp16(const float* __restrict__ x, const float* __restrict__ wa,
              const float* __restrict__ wp, _Float16* __restrict__ x16,
              _Float16* __restrict__ wa16, _Float16* __restrict__ wp16)
{
    const int n1 = (BATCH * TSEQ * CEMB) / 4;
    const int n2 = (3 * CEMB * CEMB) / 4;
    int i = blockIdx.x * 256 + threadIdx.x;
    const float* src; _Float16* dst; int j;
    if (i < n1)            { src = x;  dst = x16;  j = i; }
    else if (i < n1 + n2)  { src = wa; dst = wa16; j = i - n1; }
    else                   { src = wp; dst = wp16; j = i - n1 - n2; }
    float4 v = ((const float4*)src)[j];
    half4 h = { (_Float16)v.x, (_Float16)v.y, (_Float16)v.z, (_Float16)v.w };
    ((half4*)dst)[j] = h;
}

// ---------------------------------------------------------------------------
// GEMM staging: 128x32 fp16 tile, DMA, XOR swizzle c = pc ^ (row&3).
// ---------------------------------------------------------------------------
__device__ __forceinline__ void stage32(const _Float16* __restrict__ gbase,
                                        _Float16* __restrict__ lds,
                                        int row0, int kk, int tid)
{
#pragma unroll
    for (int p = 0; p < 2; ++p) {
        int ci  = p * 256 + tid;
        int row = ci >> 2, pcc = ci & 3;
        int c   = pcc ^ (row & 3);
        lds_dma16(gbase + (size_t)(row0 + row) * CEMB + kk + c * 8, lds + ci * 8);
    }
}

// ---------------------------------------------------------------------------
// Kernel 1: qkv = x16 @ Wa16^T. Epilogue stages C through LDS for coalesced
// half8 stores; v blocks transpose in LDS. q is pre-scaled by 8*log2e.
// ---------------------------------------------------------------------------
__global__ __launch_bounds__(256)
void qkv_gemm(const _Float16* __restrict__ A, const _Float16* __restrict__ B,
              _Float16* __restrict__ q16, _Float16* __restrict__ k16,
              _Float16* __restrict__ v16)
{
    __shared__ __align__(16) _Float16 smem[16384];   // 32 KB: dbuf tiles / C-tile
    const int tid = threadIdx.x, lane = tid & 63, wave = tid >> 6;
    const int wm = wave & 1, wn = wave >> 1;
    const int m0 = blockIdx.y * 128, n0 = blockIdx.x * 128;
    const int l15 = lane & 15, quad = lane >> 4;

    floatx4 acc[4][4];
#pragma unroll
    for (int i = 0; i < 4; ++i)
#pragma unroll
        for (int j = 0; j < 4; ++j) acc[i][j] = (floatx4){0.f, 0.f, 0.f, 0.f};

    stage32(A, smem, m0, 0, tid);
    stage32(B, smem + 8192, n0, 0, tid);
    for (int kt = 0; kt < 32; ++kt) {
        const int cur = kt & 1;
        _Float16* Asc = smem + cur * 4096;
        _Float16* Bsc = smem + 8192 + cur * 4096;
        __syncthreads();                      // drains DMA(kt)
        if (kt < 31) {
            stage32(A, smem + (cur ^ 1) * 4096, m0, (kt + 1) * 32, tid);
            stage32(B, smem + 8192 + (cur ^ 1) * 4096, n0, (kt + 1) * 32, tid);
        }
        half8 af[4], bf[4];
#pragma unroll
        for (int mt = 0; mt < 4; ++mt) {
            int row = wm * 64 + mt * 16 + l15;
            af[mt] = *(const half8*)(Asc + row * 32 + (quad ^ (row & 3)) * 8);
        }
#pragma unroll
        for (int nt = 0; nt < 4; ++nt) {
            int row = wn * 64 + nt * 16 + l15;
            bf[nt] = *(const half8*)(Bsc + row * 32 + (quad ^ (row & 3)) * 8);
        }
#pragma unroll
        for (int mt = 0; mt < 4; ++mt)
#pragma unroll
            for (int nt = 0; nt < 4; ++nt)
                acc[mt][nt] = __builtin_amdgcn_mfma_f32_16x16x32_f16(af[mt], bf[nt], acc[mt][nt], 0, 0, 0);
    }

    __syncthreads();                          // all frag reads done; reuse smem
    const int rbase = quad << 2;
    if (n0 < 2 * CEMB) {
        // --- q/k: C[t][n'] with chunk swizzle pc = (n>>3) ^ (t&15) ---
        const float scale = (n0 < CEMB) ? QSCALE : 1.0f;
#pragma unroll
        for (int mt = 0; mt < 4; ++mt)
#pragma unroll
            for (int nt = 0; nt < 4; ++nt)
#pragma unroll
                for (int r = 0; r < 4; ++r) {
                    int t = wm * 64 + mt * 16 + rbase + r;
                    int n = wn * 64 + nt * 16 + l15;
                    int pc = (n >> 3) ^ (t & 15);
                    smem[t * 128 + pc * 8 + (n & 7)] = (_Float16)(acc[mt][nt][r] * scale);
                }
        __syncthreads();
        const int chunk = tid & 7;
#pragma unroll
        for (int i = 0; i < 8; ++i) {
            int gr = (tid >> 3) + i * 32;     // 0..255: (seg,t)
            int seg = gr >> 7, t = gr & 127;
            int pc = (seg * 8 + chunk) ^ (t & 15);
            half8 v = *(const half8*)(smem + t * 128 + pc * 8);
            int gm = m0 + t, b = gm >> 11, tt = gm & (TSEQ - 1);
            int gnb = n0 + seg * 64;
            _Float16* dst;
            if (n0 < CEMB) {
                int h = gnb >> 6;
                dst = q16 + (((size_t)(b * NHEAD + h)) * TSEQ + tt) * HD;
            } else {
                int h = (gnb - CEMB) >> 6;
                dst = k16 + (((size_t)(b * NHEAD + h)) * TSEQ + tt) * HD;
            }
            *(half8*)(dst + chunk * 8) = v;
        }
    } else {
        // --- v: transpose in LDS: C[n'][t] with pc = (t>>3) ^ (n&15) ---
#pragma unroll
        for (int mt = 0; mt < 4; ++mt)
#pragma unroll
            for (int nt = 0; nt < 4; ++nt)
#pragma unroll
                for (int r = 0; r < 4; ++r) {
                    int t = wm * 64 + mt * 16 + rbase + r;
                    int n = wn * 64 + nt * 16 + l15;
                    int pc = (t >> 3) ^ (n & 15);
                    smem[n * 128 + pc * 8 + (t & 7)] = (_Float16)acc[mt][nt][r];
                }
        __syncthreads();
        const int chunk = tid & 15;           // 16 chunks of 8 along t
        const int b = m0 >> 11, tblk = m0 & (TSEQ - 1);
#pragma unroll
        for (int i = 0; i < 8; ++i) {
            int row = (tid >> 4) + i * 16;    // n' 0..127
            int pc = chunk ^ (row & 15);
            half8 v = *(const half8*)(smem + row * 128 + pc * 8);
            int c2 = n0 - 2 * CEMB + row;
            int h = c2 >> 6, d = c2 & 63;
            *(half8*)(v16 + (((size_t)(b * NHEAD + h)) * HD + d) * TSEQ + tblk + chunk * 8) = v;
        }
    }
}

// ---------------------------------------------------------------------------
// Kernel 2: flash attention. S^T = K·Q^T; P stays in registers in B-layout
// for mfma_16x16x16f16 (O^T = V^T·P^T). Cooperative: all 4 waves share each
// tile; phase 1 = tiles A+B with shared K/V frags (2x ILP), phase 2 B-only.
//
// Complementary-qtA CU residency: old same-qtA map made per-CU block-iters
// 4*(32-qtA): qtA=0 CUs ran 128 (the kernel bound) while qtA=15 CUs idled
// after 68. New map gives co-resident blocks {c,15-c,c,15-c}: every CU runs
// exactly 98 block-iters. XCD locality (bh%8==L%8) preserved.
// setprio removed (round-3: -3%, lockstep = m190 null regime).
// P-packing via v_cvt_pkrtz (halves conversion op count; RTZ ok at p<=1).
// ---------------------------------------------------------------------------
__device__ __forceinline__ void attn_tile(
    const half8& qf0, const half8& qf1,
    float& m_i, float& l_i, floatx4 (&o)[4],
    const _Float16* __restrict__ Ks, const _Float16* __restrict__ Vs,
    bool domask, int l15, int quad, int relq)
{
    floatx4 s[4];
#pragma unroll
    for (int nt = 0; nt < 4; ++nt) {
        int row = nt * 16 + l15;
        int pc0 = quad ^ (row & 7);
        half8 kf0 = *(const half8*)(Ks + row * 64 + pc0 * 8);
        half8 kf1 = *(const half8*)(Ks + row * 64 + (pc0 ^ 4) * 8);
        floatx4 z = (floatx4){0.f, 0.f, 0.f, 0.f};
        z = __builtin_amdgcn_mfma_f32_16x16x32_f16(kf0, qf0, z, 0, 0, 0);
        z = __builtin_amdgcn_mfma_f32_16x16x32_f16(kf1, qf1, z, 0, 0, 0);
        s[nt] = z;
    }
    if (domask) {
#pragma unroll
        for (int nt = 0; nt < 4; ++nt)
#pragma unroll
            for (int r = 0; r < 4; ++r)
                if (nt * 16 + quad * 4 + r > relq) s[nt][r] = -INFINITY;
    }
    float pmax = -INFINITY;
#pragma unroll
    for (int nt = 0; nt < 4; ++nt)
        pmax = fmaxf(pmax, fmaxf(fmaxf(s[nt][0], s[nt][1]), fmaxf(s[nt][2], s[nt][3])));
    // defer-max: reduce + rescale only if some lane's max grew (else alpha==1)
    if (!__all(pmax <= m_i)) {
        float mx = fmaxf(m_i, pmax);
        mx = fmaxf(mx, __shfl_xor(mx, 16, 64));
        mx = fmaxf(mx, __shfl_xor(mx, 32, 64));
        float alpha = fast_exp2(m_i - mx);
        m_i = mx;
        l_i *= alpha;
#pragma unroll
        for (int mt = 0; mt < 4; ++mt)
#pragma unroll
            for (int r = 0; r < 4; ++r) o[mt][r] *= alpha;
    }
    float rs = 0.f;
    half4 p[4];
#pragma unroll
    for (int nt = 0; nt < 4; ++nt) {
        float p0 = fast_exp2(s[nt][0] - m_i), p1 = fast_exp2(s[nt][1] - m_i);
        float p2 = fast_exp2(s[nt][2] - m_i), p3 = fast_exp2(s[nt][3] - m_i);
        rs += (p0 + p1) + (p2 + p3);
        p[nt] = pack4(p0, p1, p2, p3);
    }
    l_i += rs;   // per-lane partial; reduced once in epilogue
#pragma unroll
    for (int mt = 0; mt < 4; ++mt) {
        int d = mt * 16 + l15;
#pragma unroll
        for (int nt = 0; nt < 4; ++nt) {
            int pc = (2 * nt + (quad >> 1)) ^ (d & 7);
            half4 vf = *(const half4*)(Vs + d * 64 + pc * 8 + (quad & 1) * 4);
            o[mt] = __builtin_amdgcn_mfma_f32_16x16x16f16(vf, p[nt], o[mt], 0, 0, 0);
        }
    }
}

// dual-tile body: A and B interleaved, shared K/V fragments. B never masked
// here (kt <= qtA < qtB); A masked iff kt == qtA.
__device__ __forceinline__ void attn_tile2(
    const half8& qA0, const half8& qA1, const half8& qB0, const half8& qB1,
    float& mAi, float& lAi, floatx4 (&oA)[4],
    float& mBi, float& lBi, floatx4 (&oB)[4],
    const _Float16* __restrict__ Ks, const _Float16* __restrict__ Vs,
    bool maskA, int l15, int quad, int relq)
{
    floatx4 sA[4], sB[4];
#pragma unroll
    for (int nt = 0; nt < 4; ++nt) {
        int row = nt * 16 + l15;
        int pc0 = quad ^ (row & 7);
        half8 kf0 = *(const half8*)(Ks + row * 64 + pc0 * 8);
        half8 kf1 = *(const half8*)(Ks + row * 64 + (pc0 ^ 4) * 8);
        floatx4 zA = (floatx4){0.f, 0.f, 0.f, 0.f};
        floatx4 zB = (floatx4){0.f, 0.f, 0.f, 0.f};
        zA = __builtin_amdgcn_mfma_f32_16x16x32_f16(kf0, qA0, zA, 0, 0, 0);
        zB = __builtin_amdgcn_mfma_f32_16x16x32_f16(kf0, qB0, zB, 0, 0, 0);
        zA = __builtin_amdgcn_mfma_f32_16x16x32_f16(kf1, qA1, zA, 0, 0, 0);
        zB = __builtin_amdgcn_mfma_f32_16x16x32_f16(kf1, qB1, zB, 0, 0, 0);
        sA[nt] = zA; sB[nt] = zB;
    }
    if (maskA) {
#pragma unroll
        for (int nt = 0; nt < 4; ++nt)
#pragma unroll
            for (int r = 0; r < 4; ++r)
                if (nt * 16 + quad * 4 + r > relq) sA[nt][r] = -INFINITY;
    }
    // per-lane maxes (two independent chains)
    float pA = -INFINITY, pB = -INFINITY;
#pragma unroll
    for (int nt = 0; nt < 4; ++nt) {
        pA = fmaxf(pA, fmaxf(fmaxf(sA[nt][0], sA[nt][1]), fmaxf(sA[nt][2], sA[nt][3])));
        pB = fmaxf(pB, fmaxf(fmaxf(sB[nt][0], sB[nt][1]), fmaxf(sB[nt][2], sB[nt][3])));
    }
    if (!__all((pA <= mAi) && (pB <= mBi))) {
        float mxA = fmaxf(mAi, pA), mxB = fmaxf(mBi, pB);
        mxA = fmaxf(mxA, __shfl_xor(mxA, 16, 64));
        mxB = fmaxf(mxB, __shfl_xor(mxB, 16, 64));
        mxA = fmaxf(mxA, __shfl_xor(mxA, 32, 64));
        mxB = fmaxf(mxB, __shfl_xor(mxB, 32, 64));
        float alA = fast_exp2(mAi - mxA);
        float alB = fast_exp2(mBi - mxB);
        mAi = mxA; mBi = mxB;
        lAi *= alA; lBi *= alB;
#pragma unroll
        for (int mt = 0; mt < 4; ++mt)
#pragma unroll
            for (int r = 0; r < 4; ++r) { oA[mt][r] *= alA; oB[mt][r] *= alB; }
    }
    float rsA = 0.f, rsB = 0.f;
    half4 pAh[4], pBh[4];
#pragma unroll
    for (int nt = 0; nt < 4; ++nt) {
        float a0 = fast_exp2(sA[nt][0] - mAi), b0 = fast_exp2(sB[nt][0] - mBi);
        float a1 = fast_exp2(sA[nt][1] - mAi), b1 = fast_exp2(sB[nt][1] - mBi);
        float a2 = fast_exp2(sA[nt][2] - mAi), b2 = fast_exp2(sB[nt][2] - mBi);
        float a3 = fast_exp2(sA[nt][3] - mAi), b3 = fast_exp2(sB[nt][3] - mBi);
        rsA += (a0 + a1) + (a2 + a3);
        rsB += (b0 + b1) + (b2 + b3);
        pAh[nt] = pack4(a0, a1, a2, a3);
        pBh[nt] = pack4(b0, b1, b2, b3);
    }
    lAi += rsA; lBi += rsB;   // per-lane partials
    // PV with shared V fragments
#pragma unroll
    for (int mt = 0; mt < 4; ++mt) {
        int d = mt * 16 + l15;
#pragma unroll
        for (int nt = 0; nt < 4; ++nt) {
            int pc = (2 * nt + (quad >> 1)) ^ (d & 7);
            half4 vf = *(const half4*)(Vs + d * 64 + pc * 8 + (quad & 1) * 4);
            oA[mt] = __builtin_amdgcn_mfma_f32_16x16x16f16(vf, pAh[nt], oA[mt], 0, 0, 0);
            oB[mt] = __builtin_amdgcn_mfma_f32_16x16x16f16(vf, pBh[nt], oB[mt], 0, 0, 0);
        }
    }
}

__global__ __launch_bounds__(256)
void attn_fwd(const _Float16* __restrict__ q16, const _Float16* __restrict__ k16,
              const _Float16* __restrict__ v16, _Float16* __restrict__ o16)
{
    __shared__ __align__(16) _Float16 Ks[2][64 * 64];
    __shared__ __align__(16) _Float16 Vs[2][64 * 64];
    const int tid = threadIdx.x, lane = tid & 63, wave = tid >> 6;
    const int l15 = lane & 15, quad = lane >> 4;

    // Complementary-qtA remap. L = x + 16y; xcd = L%8 (round-robin dispatch);
    // r = L>>3 indexes the XCD's 128 blocks; u = r&31 = CU slot, v = r>>5 =
    // residency round. qtA = c for even rounds, 15-c for odd -> each CU's 4
    // blocks run (32-c)+(17+c)+(32-c)+(17+c) = 98 iterations, uniformly.
    // bh = xcd + 8w keeps all of a bh's blocks on one XCD (L2-resident K/V).
    const int L   = blockIdx.x + 16 * blockIdx.y;
    const int xcd = L & 7;
    const int r   = L >> 3;            // 0..127
    const int u   = r & 31;            // CU slot on XCD
    const int v   = r >> 5;            // round 0..3
    const int c   = u & 15;
    const int qtA = (v & 1) ? (15 - c) : c;   // 0..15
    const int w   = (u >> 4) + 2 * v;         // 0..7
    const int bh  = xcd + 8 * w;              // 0..63
    const int qtB = 31 - qtA;                 // 16..31
    const int b = bh >> 4, h = bh & 15;
    const int q0A = qtA * 64, q0B = qtB * 64;
    const _Float16* qp = q16 + (size_t)bh * TSEQ * HD;
    const _Float16* kp = k16 + (size_t)bh * TSEQ * HD;
    const _Float16* vp = v16 + (size_t)bh * HD * TSEQ;

    const int relq = wave * 16 + l15;
    half8 qA0 = *(const half8*)(qp + (size_t)(q0A + relq) * HD + quad * 8);
    half8 qA1 = *(const half8*)(qp + (size_t)(q0A + relq) * HD + 32 + quad * 8);
    half8 qB0 = *(const half8*)(qp + (size_t)(q0B + relq) * HD + quad * 8);
    half8 qB1 = *(const half8*)(qp + (size_t)(q0B + relq) * HD + 32 + quad * 8);

    float mA = -INFINITY, lA = 0.f, mB = -INFINITY, lB = 0.f;
    floatx4 oA[4], oB[4];
#pragma unroll
    for (int mt = 0; mt < 4; ++mt) { oA[mt] = (floatx4){0.f,0.f,0.f,0.f}; oB[mt] = (floatx4){0.f,0.f,0.f,0.f}; }

#define STAGE_KV(kt0, buf)                                                     \
    {                                                                          \
        _Float16* kd = Ks[buf];                                                \
        _Float16* vd = Vs[buf];                                                \
        _Pragma("unroll")                                                      \
        for (int p = 0; p < 2; ++p) {                                          \
            int ci = p * 256 + tid;                                            \
            int row = ci >> 3;                                                 \
            int c2 = (ci & 7) ^ (row & 7);                                     \
            lds_dma16(kp + (size_t)((kt0) + row) * HD + c2 * 8, kd + ci * 8);  \
            lds_dma16(vp + (size_t)row * TSEQ + (kt0) + c2 * 8, vd + ci * 8);  \
        }                                                                      \
    }

    STAGE_KV(0, 0);
    // phase 1: kt = 0..qtA — both tiles, shared K/V frags, interleaved ILP
    for (int kt = 0; kt <= qtA; ++kt) {
        const int cur = kt & 1;
        __syncthreads();
        STAGE_KV((kt + 1) * 64, cur ^ 1);     // kt+1 <= qtA+1 <= qtB: valid
        attn_tile2(qA0, qA1, qB0, qB1, mA, lA, oA, mB, lB, oB,
                   Ks[cur], Vs[cur], (kt == qtA), l15, quad, relq);
    }
    // phase 2: kt = qtA+1..qtB — B only
    for (int kt = qtA + 1; kt <= qtB; ++kt) {
        const int cur = kt & 1;
        __syncthreads();
        if (kt < qtB) STAGE_KV((kt + 1) * 64, cur ^ 1);
        attn_tile(qB0, qB1, mB, lB, oB, Ks[cur], Vs[cur], (kt == qtB), l15, quad, relq);
    }
#undef STAGE_KV

    // reduce per-lane l partials across the 4 lanes sharing each q-row
    lA += __shfl_xor(lA, 16, 64); lA += __shfl_xor(lA, 32, 64);
    lB += __shfl_xor(lB, 16, 64); lB += __shfl_xor(lB, 32, 64);
    const float invA = 1.f / lA, invB = 1.f / lB;
    const size_t baseA = ((size_t)(b * TSEQ + q0A + relq)) * CEMB + h * HD + quad * 4;
    const size_t baseB = ((size_t)(b * TSEQ + q0B + relq)) * CEMB + h * HD + quad * 4;
#pragma unroll
    for (int mt = 0; mt < 4; ++mt) {
        half4 ha = { (_Float16)(oA[mt][0] * invA), (_Float16)(oA[mt][1] * invA),
                     (_Float16)(oA[mt][2] * invA), (_Float16)(oA[mt][3] * invA) };
        half4 hb = { (_Float16)(oB[mt][0] * invB), (_Float16)(oB[mt][1] * invB),
                     (_Float16)(oB[mt][2] * invB), (_Float16)(oB[mt][3] * invB) };
        *(half4*)(o16 + baseA + mt * 16) = ha;
        *(half4*)(o16 + baseB + mt * 16) = hb;
    }
}

// ---------------------------------------------------------------------------
// Kernel 3: y = attn16 @ Wp16^T + b_proj, fp32 out. 128x128 tile (mirror of
// qkv_gemm's proven loop: 16 MFMA/K-step/wave), grid (8, 64) = 512 blocks.
// ---------------------------------------------------------------------------
__global__ __launch_bounds__(256)
void proj_gemm(const _Float16* __restrict__ A, const _Float16* __restrict__ B,
               const float* __restrict__ bias, float* __restrict__ out)
{
    __shared__ __align__(16) _Float16 smem[16384];   // 32 KB dbuf tiles
    const int tid = threadIdx.x, lane = tid & 63, wave = tid >> 6;
    const int wm = wave & 1, wn = wave >> 1;
    const int m0 = blockIdx.y * 128, n0 = blockIdx.x * 128;
    const int l15 = lane & 15, quad = lane >> 4;

    floatx4 acc[4][4];
#pragma unroll
    for (int i = 0; i < 4; ++i)
#pragma unroll
        for (int j = 0; j < 4; ++j) acc[i][j] = (floatx4){0.f, 0.f, 0.f, 0.f};

    stage32(A, smem, m0, 0, tid);
    stage32(B, smem + 8192, n0, 0, tid);
    for (int kt = 0; kt < 32; ++kt) {
        const int cur = kt & 1;
        _Float16* Asc = smem + cur * 4096;
        _Float16* Bsc = smem + 8192 + cur * 4096;
        __syncthreads();                      // drains DMA(kt)
        if (kt < 31) {
            stage32(A, smem + (cur ^ 1) * 4096, m0, (kt + 1) * 32, tid);
            stage32(B, smem + 8192 + (cur ^ 1) * 4096, n0, (kt + 1) * 32, tid);
        }
        half8 af[4], bf[4];
#pragma unroll
        for (int mt = 0; mt < 4; ++mt) {
            int row = wm * 64 + mt * 16 + l15;
            af[mt] = *(const half8*)(Asc + row * 32 + (quad ^ (row & 3)) * 8);
        }
#pragma unroll
        for (int nt = 0; nt < 4; ++nt) {
            int row = wn * 64 + nt * 16 + l15;
            bf[nt] = *(const half8*)(Bsc + row * 32 + (quad ^ (row & 3)) * 8);
        }
#pragma unroll
        for (int mt = 0; mt < 4; ++mt)
#pragma unroll
            for (int nt = 0; nt < 4; ++nt)
                acc[mt][nt] = __builtin_amdgcn_mfma_f32_16x16x32_f16(af[mt], bf[nt], acc[mt][nt], 0, 0, 0);
    }

    const int rbase = quad << 2;
#pragma unroll
    for (int mt = 0; mt < 4; ++mt)
#pragma unroll
        for (int nt = 0; nt < 4; ++nt) {
            int gn = n0 + wn * 64 + nt * 16 + l15;
            float bb = bias[gn];
#pragma unroll
            for (int r = 0; r < 4; ++r) {
                int gm = m0 + wm * 64 + mt * 16 + rbase + r;
                out[(size_t)gm * CEMB + gn] = acc[mt][nt][r] + bb;
            }
        }
}

// ---------------------------------------------------------------------------
extern "C" void kernel_launch(void* const* d_in, const int* in_sizes, int n_in,
                              void* d_out, int out_size, void* d_ws, size_t ws_size,
                              hipStream_t stream) {
    const float* x     = (const float*)d_in[0];
    const float* Wattn = (const float*)d_in[1];
    const float* Wproj = (const float*)d_in[2];
    const float* bproj = (const float*)d_in[3];
    float* out = (float*)d_out;

    const size_t nx  = (size_t)BATCH * TSEQ * CEMB;
    const size_t nwa = (size_t)3 * CEMB * CEMB;
    const size_t nwp = (size_t)CEMB * CEMB;
    const size_t per = (size_t)BATCH * NHEAD * TSEQ * HD;

    _Float16* x16    = (_Float16*)d_ws;
    _Float16* wa16   = x16 + nx;
    _Float16* wp16   = wa16 + nwa;
    _Float16* q16    = wp16 + nwp;
    _Float16* k16    = q16 + per;
    _Float16* v16    = k16 + per;
    _Float16* attn16 = x16;   // alias: x16 fully consumed before attn writes

    const int nconv = (int)((nx + nwa + nwp) / 4);
    cvt_fp16<<<nconv / 256, 256, 0, stream>>>(x, Wattn, Wproj, x16, wa16, wp16);
    qkv_gemm<<<dim3(3 * CEMB / 128, MROWS / 128), 256, 0, stream>>>(x16, wa16, q16, k16, v16);
    attn_fwd<<<dim3(16, BATCH * NHEAD), 256, 0, stream>>>(q16, k16, v16, attn16);
    proj_gemm<<<dim3(CEMB / 128, MROWS / 128), 256, 0, stream>>>(attn16, wp16, bproj, out);
}

// Round 6
// 281.707 us; speedup vs baseline: 1.0149x; 1.0149x over previous
//
#include <hip/hip_runtime.h>
#include <math.h>

#define BATCH 4
#define TSEQ  2048
#define CEMB  1024
#define NHEAD 16
#define HD    64
#define MROWS (BATCH * TSEQ)   // 8192
#define QSCALE 11.5415603271f  // 8 * log2(e): softmax runs in exp2 domain

typedef _Float16 half8 __attribute__((ext_vector_type(8)));
typedef _Float16 half4 __attribute__((ext_vector_type(4)));
typedef _Float16 half2 __attribute__((ext_vector_type(2)));
typedef float    floatx4 __attribute__((ext_vector_type(4)));

#define GLOBAL_AS __attribute__((address_space(1)))
#define LDS_AS    __attribute__((address_space(3)))

__device__ __forceinline__ void lds_dma16(const _Float16* g, _Float16* l) {
    __builtin_amdgcn_global_load_lds((const GLOBAL_AS unsigned int*)g,
                                     (LDS_AS unsigned int*)l, 16, 0, 0);
}

// raw v_exp_f32 (2^x). VALU interlocks handle the hazard; exp2(-inf)=0.
__device__ __forceinline__ float fast_exp2(float x) {
    float r; asm("v_exp_f32 %0, %1" : "=v"(r) : "v"(x)); return r;
}

// packed f32->f16 conversion: 2 v_cvt_pkrtz instead of ~6 cvt+pack ops.
// builtin returns __fp16x2; bit_cast to our _Float16-based half2.
__device__ __forceinline__ half4 pack4(float a0, float a1, float a2, float a3) {
    half2 lo = __builtin_bit_cast(half2, __builtin_amdgcn_cvt_pkrtz(a0, a1));
    half2 hi = __builtin_bit_cast(half2, __builtin_amdgcn_cvt_pkrtz(a2, a3));
    return (half4){lo[0], lo[1], hi[0], hi[1]};
}

// ---------------------------------------------------------------------------
// Kernel 0: fp32 -> fp16 convert prepass (float4 -> half4)
// ---------------------------------------------------------------------------
__global__ __launch_bounds__(256)
void cvt_fp16(const float* __restrict__ x, const float* __restrict__ wa,
              const float* __restrict__ wp, _Float16* __restrict__ x16,
              _Float16* __restrict__ wa16, _Float16* __restrict__ wp16)
{
    const int n1 = (BATCH * TSEQ * CEMB) / 4;
    const int n2 = (3 * CEMB * CEMB) / 4;
    int i = blockIdx.x * 256 + threadIdx.x;
    const float* src; _Float16* dst; int j;
    if (i < n1)            { src = x;  dst = x16;  j = i; }
    else if (i < n1 + n2)  { src = wa; dst = wa16; j = i - n1; }
    else                   { src = wp; dst = wp16; j = i - n1 - n2; }
    float4 v = ((const float4*)src)[j];
    half4 h = { (_Float16)v.x, (_Float16)v.y, (_Float16)v.z, (_Float16)v.w };
    ((half4*)dst)[j] = h;
}

// ---------------------------------------------------------------------------
// GEMM staging: 128x32 fp16 tile, DMA, XOR swizzle c = pc ^ (row&3).
// ---------------------------------------------------------------------------
__device__ __forceinline__ void stage32(const _Float16* __restrict__ gbase,
                                        _Float16* __restrict__ lds,
                                        int row0, int kk, int tid)
{
#pragma unroll
    for (int p = 0; p < 2; ++p) {
        int ci  = p * 256 + tid;
        int row = ci >> 2, pcc = ci & 3;
        int c   = pcc ^ (row & 3);
        lds_dma16(gbase + (size_t)(row0 + row) * CEMB + kk + c * 8, lds + ci * 8);
    }
}

// ---------------------------------------------------------------------------
// Kernel 1: qkv = x16 @ Wa16^T. Epilogue stages C through LDS for coalesced
// half8 stores; v blocks transpose in LDS. q is pre-scaled by 8*log2e.
// ---------------------------------------------------------------------------
__global__ __launch_bounds__(256)
void qkv_gemm(const _Float16* __restrict__ A, const _Float16* __restrict__ B,
              _Float16* __restrict__ q16, _Float16* __restrict__ k16,
              _Float16* __restrict__ v16)
{
    __shared__ __align__(16) _Float16 smem[16384];   // 32 KB: dbuf tiles / C-tile
    const int tid = threadIdx.x, lane = tid & 63, wave = tid >> 6;
    const int wm = wave & 1, wn = wave >> 1;
    const int m0 = blockIdx.y * 128, n0 = blockIdx.x * 128;
    const int l15 = lane & 15, quad = lane >> 4;

    floatx4 acc[4][4];
#pragma unroll
    for (int i = 0; i < 4; ++i)
#pragma unroll
        for (int j = 0; j < 4; ++j) acc[i][j] = (floatx4){0.f, 0.f, 0.f, 0.f};

    stage32(A, smem, m0, 0, tid);
    stage32(B, smem + 8192, n0, 0, tid);
    for (int kt = 0; kt < 32; ++kt) {
        const int cur = kt & 1;
        _Float16* Asc = smem + cur * 4096;
        _Float16* Bsc = smem + 8192 + cur * 4096;
        __syncthreads();                      // drains DMA(kt)
        if (kt < 31) {
            stage32(A, smem + (cur ^ 1) * 4096, m0, (kt + 1) * 32, tid);
            stage32(B, smem + 8192 + (cur ^ 1) * 4096, n0, (kt + 1) * 32, tid);
        }
        half8 af[4], bf[4];
#pragma unroll
        for (int mt = 0; mt < 4; ++mt) {
            int row = wm * 64 + mt * 16 + l15;
            af[mt] = *(const half8*)(Asc + row * 32 + (quad ^ (row & 3)) * 8);
        }
#pragma unroll
        for (int nt = 0; nt < 4; ++nt) {
            int row = wn * 64 + nt * 16 + l15;
            bf[nt] = *(const half8*)(Bsc + row * 32 + (quad ^ (row & 3)) * 8);
        }
#pragma unroll
        for (int mt = 0; mt < 4; ++mt)
#pragma unroll
            for (int nt = 0; nt < 4; ++nt)
                acc[mt][nt] = __builtin_amdgcn_mfma_f32_16x16x32_f16(af[mt], bf[nt], acc[mt][nt], 0, 0, 0);
    }

    __syncthreads();                          // all frag reads done; reuse smem
    const int rbase = quad << 2;
    if (n0 < 2 * CEMB) {
        // --- q/k: C[t][n'] with chunk swizzle pc = (n>>3) ^ (t&15) ---
        const float scale = (n0 < CEMB) ? QSCALE : 1.0f;
#pragma unroll
        for (int mt = 0; mt < 4; ++mt)
#pragma unroll
            for (int nt = 0; nt < 4; ++nt)
#pragma unroll
                for (int r = 0; r < 4; ++r) {
                    int t = wm * 64 + mt * 16 + rbase + r;
                    int n = wn * 64 + nt * 16 + l15;
                    int pc = (n >> 3) ^ (t & 15);
                    smem[t * 128 + pc * 8 + (n & 7)] = (_Float16)(acc[mt][nt][r] * scale);
                }
        __syncthreads();
        const int chunk = tid & 7;
#pragma unroll
        for (int i = 0; i < 8; ++i) {
            int gr = (tid >> 3) + i * 32;     // 0..255: (seg,t)
            int seg = gr >> 7, t = gr & 127;
            int pc = (seg * 8 + chunk) ^ (t & 15);
            half8 v = *(const half8*)(smem + t * 128 + pc * 8);
            int gm = m0 + t, b = gm >> 11, tt = gm & (TSEQ - 1);
            int gnb = n0 + seg * 64;
            _Float16* dst;
            if (n0 < CEMB) {
                int h = gnb >> 6;
                dst = q16 + (((size_t)(b * NHEAD + h)) * TSEQ + tt) * HD;
            } else {
                int h = (gnb - CEMB) >> 6;
                dst = k16 + (((size_t)(b * NHEAD + h)) * TSEQ + tt) * HD;
            }
            *(half8*)(dst + chunk * 8) = v;
        }
    } else {
        // --- v: transpose in LDS: C[n'][t] with pc = (t>>3) ^ (n&15) ---
#pragma unroll
        for (int mt = 0; mt < 4; ++mt)
#pragma unroll
            for (int nt = 0; nt < 4; ++nt)
#pragma unroll
                for (int r = 0; r < 4; ++r) {
                    int t = wm * 64 + mt * 16 + rbase + r;
                    int n = wn * 64 + nt * 16 + l15;
                    int pc = (t >> 3) ^ (n & 15);
                    smem[n * 128 + pc * 8 + (t & 7)] = (_Float16)acc[mt][nt][r];
                }
        __syncthreads();
        const int chunk = tid & 15;           // 16 chunks of 8 along t
        const int b = m0 >> 11, tblk = m0 & (TSEQ - 1);
#pragma unroll
        for (int i = 0; i < 8; ++i) {
            int row = (tid >> 4) + i * 16;    // n' 0..127
            int pc = chunk ^ (row & 15);
            half8 v = *(const half8*)(smem + row * 128 + pc * 8);
            int c2 = n0 - 2 * CEMB + row;
            int h = c2 >> 6, d = c2 & 63;
            *(half8*)(v16 + (((size_t)(b * NHEAD + h)) * HD + d) * TSEQ + tblk + chunk * 8) = v;
        }
    }
}

// ---------------------------------------------------------------------------
// Kernel 2: flash attention. S^T = K·Q^T; P stays in registers in B-layout
// for mfma_16x16x16f16 (O^T = V^T·P^T). Cooperative: all 4 waves share each
// tile; phase 1 = tiles A+B with shared K/V frags (2x ILP), phase 2 B-only.
//
// Config = measured-best per component:
//  - R2 same-qtA XCD remap (attn 90.1us). Complementary-qtA remap (R5,
//    94.2us) REVERTED: dispatch is dynamic, static per-CU balance model was
//    wrong; scheduling interventions 0-for-3 (wave-split, setprio, comp-map).
//  - defer-max (exact, THR=0) + per-lane l partials (epilogue reduce).
//  - no setprio (R3: -3%, lockstep barrier = m190 null regime).
//  - cvt_pkrtz P-packing kept (theory: strictly fewer VALU ops; this round
//    isolates it under the R2 map).
// ---------------------------------------------------------------------------
__device__ __forceinline__ void attn_tile(
    const half8& qf0, const half8& qf1,
    float& m_i, float& l_i, floatx4 (&o)[4],
    const _Float16* __restrict__ Ks, const _Float16* __restrict__ Vs,
    bool domask, int l15, int quad, int relq)
{
    floatx4 s[4];
#pragma unroll
    for (int nt = 0; nt < 4; ++nt) {
        int row = nt * 16 + l15;
        int pc0 = quad ^ (row & 7);
        half8 kf0 = *(const half8*)(Ks + row * 64 + pc0 * 8);
        half8 kf1 = *(const half8*)(Ks + row * 64 + (pc0 ^ 4) * 8);
        floatx4 z = (floatx4){0.f, 0.f, 0.f, 0.f};
        z = __builtin_amdgcn_mfma_f32_16x16x32_f16(kf0, qf0, z, 0, 0, 0);
        z = __builtin_amdgcn_mfma_f32_16x16x32_f16(kf1, qf1, z, 0, 0, 0);
        s[nt] = z;
    }
    if (domask) {
#pragma unroll
        for (int nt = 0; nt < 4; ++nt)
#pragma unroll
            for (int r = 0; r < 4; ++r)
                if (nt * 16 + quad * 4 + r > relq) s[nt][r] = -INFINITY;
    }
    float pmax = -INFINITY;
#pragma unroll
    for (int nt = 0; nt < 4; ++nt)
        pmax = fmaxf(pmax, fmaxf(fmaxf(s[nt][0], s[nt][1]), fmaxf(s[nt][2], s[nt][3])));
    // defer-max: reduce + rescale only if some lane's max grew (else alpha==1)
    if (!__all(pmax <= m_i)) {
        float mx = fmaxf(m_i, pmax);
        mx = fmaxf(mx, __shfl_xor(mx, 16, 64));
        mx = fmaxf(mx, __shfl_xor(mx, 32, 64));
        float alpha = fast_exp2(m_i - mx);
        m_i = mx;
        l_i *= alpha;
#pragma unroll
        for (int mt = 0; mt < 4; ++mt)
#pragma unroll
            for (int r = 0; r < 4; ++r) o[mt][r] *= alpha;
    }
    float rs = 0.f;
    half4 p[4];
#pragma unroll
    for (int nt = 0; nt < 4; ++nt) {
        float p0 = fast_exp2(s[nt][0] - m_i), p1 = fast_exp2(s[nt][1] - m_i);
        float p2 = fast_exp2(s[nt][2] - m_i), p3 = fast_exp2(s[nt][3] - m_i);
        rs += (p0 + p1) + (p2 + p3);
        p[nt] = pack4(p0, p1, p2, p3);
    }
    l_i += rs;   // per-lane partial; reduced once in epilogue
#pragma unroll
    for (int mt = 0; mt < 4; ++mt) {
        int d = mt * 16 + l15;
#pragma unroll
        for (int nt = 0; nt < 4; ++nt) {
            int pc = (2 * nt + (quad >> 1)) ^ (d & 7);
            half4 vf = *(const half4*)(Vs + d * 64 + pc * 8 + (quad & 1) * 4);
            o[mt] = __builtin_amdgcn_mfma_f32_16x16x16f16(vf, p[nt], o[mt], 0, 0, 0);
        }
    }
}

// dual-tile body: A and B interleaved, shared K/V fragments. B never masked
// here (kt <= qtA < qtB); A masked iff kt == qtA.
__device__ __forceinline__ void attn_tile2(
    const half8& qA0, const half8& qA1, const half8& qB0, const half8& qB1,
    float& mAi, float& lAi, floatx4 (&oA)[4],
    float& mBi, float& lBi, floatx4 (&oB)[4],
    const _Float16* __restrict__ Ks, const _Float16* __restrict__ Vs,
    bool maskA, int l15, int quad, int relq)
{
    floatx4 sA[4], sB[4];
#pragma unroll
    for (int nt = 0; nt < 4; ++nt) {
        int row = nt * 16 + l15;
        int pc0 = quad ^ (row & 7);
        half8 kf0 = *(const half8*)(Ks + row * 64 + pc0 * 8);
        half8 kf1 = *(const half8*)(Ks + row * 64 + (pc0 ^ 4) * 8);
        floatx4 zA = (floatx4){0.f, 0.f, 0.f, 0.f};
        floatx4 zB = (floatx4){0.f, 0.f, 0.f, 0.f};
        zA = __builtin_amdgcn_mfma_f32_16x16x32_f16(kf0, qA0, zA, 0, 0, 0);
        zB = __builtin_amdgcn_mfma_f32_16x16x32_f16(kf0, qB0, zB, 0, 0, 0);
        zA = __builtin_amdgcn_mfma_f32_16x16x32_f16(kf1, qA1, zA, 0, 0, 0);
        zB = __builtin_amdgcn_mfma_f32_16x16x32_f16(kf1, qB1, zB, 0, 0, 0);
        sA[nt] = zA; sB[nt] = zB;
    }
    if (maskA) {
#pragma unroll
        for (int nt = 0; nt < 4; ++nt)
#pragma unroll
            for (int r = 0; r < 4; ++r)
                if (nt * 16 + quad * 4 + r > relq) sA[nt][r] = -INFINITY;
    }
    // per-lane maxes (two independent chains)
    float pA = -INFINITY, pB = -INFINITY;
#pragma unroll
    for (int nt = 0; nt < 4; ++nt) {
        pA = fmaxf(pA, fmaxf(fmaxf(sA[nt][0], sA[nt][1]), fmaxf(sA[nt][2], sA[nt][3])));
        pB = fmaxf(pB, fmaxf(fmaxf(sB[nt][0], sB[nt][1]), fmaxf(sB[nt][2], sB[nt][3])));
    }
    if (!__all((pA <= mAi) && (pB <= mBi))) {
        float mxA = fmaxf(mAi, pA), mxB = fmaxf(mBi, pB);
        mxA = fmaxf(mxA, __shfl_xor(mxA, 16, 64));
        mxB = fmaxf(mxB, __shfl_xor(mxB, 16, 64));
        mxA = fmaxf(mxA, __shfl_xor(mxA, 32, 64));
        mxB = fmaxf(mxB, __shfl_xor(mxB, 32, 64));
        float alA = fast_exp2(mAi - mxA);
        float alB = fast_exp2(mBi - mxB);
        mAi = mxA; mBi = mxB;
        lAi *= alA; lBi *= alB;
#pragma unroll
        for (int mt = 0; mt < 4; ++mt)
#pragma unroll
            for (int r = 0; r < 4; ++r) { oA[mt][r] *= alA; oB[mt][r] *= alB; }
    }
    float rsA = 0.f, rsB = 0.f;
    half4 pAh[4], pBh[4];
#pragma unroll
    for (int nt = 0; nt < 4; ++nt) {
        float a0 = fast_exp2(sA[nt][0] - mAi), b0 = fast_exp2(sB[nt][0] - mBi);
        float a1 = fast_exp2(sA[nt][1] - mAi), b1 = fast_exp2(sB[nt][1] - mBi);
        float a2 = fast_exp2(sA[nt][2] - mAi), b2 = fast_exp2(sB[nt][2] - mBi);
        float a3 = fast_exp2(sA[nt][3] - mAi), b3 = fast_exp2(sB[nt][3] - mBi);
        rsA += (a0 + a1) + (a2 + a3);
        rsB += (b0 + b1) + (b2 + b3);
        pAh[nt] = pack4(a0, a1, a2, a3);
        pBh[nt] = pack4(b0, b1, b2, b3);
    }
    lAi += rsA; lBi += rsB;   // per-lane partials
    // PV with shared V fragments
#pragma unroll
    for (int mt = 0; mt < 4; ++mt) {
        int d = mt * 16 + l15;
#pragma unroll
        for (int nt = 0; nt < 4; ++nt) {
            int pc = (2 * nt + (quad >> 1)) ^ (d & 7);
            half4 vf = *(const half4*)(Vs + d * 64 + pc * 8 + (quad & 1) * 4);
            oA[mt] = __builtin_amdgcn_mfma_f32_16x16x16f16(vf, pAh[nt], oA[mt], 0, 0, 0);
            oB[mt] = __builtin_amdgcn_mfma_f32_16x16x16f16(vf, pBh[nt], oB[mt], 0, 0, 0);
        }
    }
}

__global__ __launch_bounds__(256)
void attn_fwd(const _Float16* __restrict__ q16, const _Float16* __restrict__ k16,
              const _Float16* __restrict__ v16, _Float16* __restrict__ o16)
{
    __shared__ __align__(16) _Float16 Ks[2][64 * 64];
    __shared__ __align__(16) _Float16 Vs[2][64 * 64];
    const int tid = threadIdx.x, lane = tid & 63, wave = tid >> 6;
    const int l15 = lane & 15, quad = lane >> 4;

    // R2 remap (measured best): L = x + 16*y. XCD = L%8 (round-robin
    // dispatch). Each XCD owns 8 bh -> its K/V stays L2-resident
    // (FETCH 128MB -> 25MB measured).
    const int L   = blockIdx.x + 16 * blockIdx.y;
    const int qtA = (L >> 3) & 15;             // 0..15
    const int bh  = (L & 7) + ((L >> 7) << 3); // 0..63
    const int qtB = 31 - qtA;                  // 16..31
    const int b = bh >> 4, h = bh & 15;
    const int q0A = qtA * 64, q0B = qtB * 64;
    const _Float16* qp = q16 + (size_t)bh * TSEQ * HD;
    const _Float16* kp = k16 + (size_t)bh * TSEQ * HD;
    const _Float16* vp = v16 + (size_t)bh * HD * TSEQ;

    const int relq = wave * 16 + l15;
    half8 qA0 = *(const half8*)(qp + (size_t)(q0A + relq) * HD + quad * 8);
    half8 qA1 = *(const half8*)(qp + (size_t)(q0A + relq) * HD + 32 + quad * 8);
    half8 qB0 = *(const half8*)(qp + (size_t)(q0B + relq) * HD + quad * 8);
    half8 qB1 = *(const half8*)(qp + (size_t)(q0B + relq) * HD + 32 + quad * 8);

    float mA = -INFINITY, lA = 0.f, mB = -INFINITY, lB = 0.f;
    floatx4 oA[4], oB[4];
#pragma unroll
    for (int mt = 0; mt < 4; ++mt) { oA[mt] = (floatx4){0.f,0.f,0.f,0.f}; oB[mt] = (floatx4){0.f,0.f,0.f,0.f}; }

#define STAGE_KV(kt0, buf)                                                     \
    {                                                                          \
        _Float16* kd = Ks[buf];                                                \
        _Float16* vd = Vs[buf];                                                \
        _Pragma("unroll")                                                      \
        for (int p = 0; p < 2; ++p) {                                          \
            int ci = p * 256 + tid;                                            \
            int row = ci >> 3;                                                 \
            int c2 = (ci & 7) ^ (row & 7);                                     \
            lds_dma16(kp + (size_t)((kt0) + row) * HD + c2 * 8, kd + ci * 8);  \
            lds_dma16(vp + (size_t)row * TSEQ + (kt0) + c2 * 8, vd + ci * 8);  \
        }                                                                      \
    }

    STAGE_KV(0, 0);
    // phase 1: kt = 0..qtA — both tiles, shared K/V frags, interleaved ILP
    for (int kt = 0; kt <= qtA; ++kt) {
        const int cur = kt & 1;
        __syncthreads();
        STAGE_KV((kt + 1) * 64, cur ^ 1);     // kt+1 <= qtA+1 <= qtB: valid
        attn_tile2(qA0, qA1, qB0, qB1, mA, lA, oA, mB, lB, oB,
                   Ks[cur], Vs[cur], (kt == qtA), l15, quad, relq);
    }
    // phase 2: kt = qtA+1..qtB — B only
    for (int kt = qtA + 1; kt <= qtB; ++kt) {
        const int cur = kt & 1;
        __syncthreads();
        if (kt < qtB) STAGE_KV((kt + 1) * 64, cur ^ 1);
        attn_tile(qB0, qB1, mB, lB, oB, Ks[cur], Vs[cur], (kt == qtB), l15, quad, relq);
    }
#undef STAGE_KV

    // reduce per-lane l partials across the 4 lanes sharing each q-row
    lA += __shfl_xor(lA, 16, 64); lA += __shfl_xor(lA, 32, 64);
    lB += __shfl_xor(lB, 16, 64); lB += __shfl_xor(lB, 32, 64);
    const float invA = 1.f / lA, invB = 1.f / lB;
    const size_t baseA = ((size_t)(b * TSEQ + q0A + relq)) * CEMB + h * HD + quad * 4;
    const size_t baseB = ((size_t)(b * TSEQ + q0B + relq)) * CEMB + h * HD + quad * 4;
#pragma unroll
    for (int mt = 0; mt < 4; ++mt) {
        half4 ha = { (_Float16)(oA[mt][0] * invA), (_Float16)(oA[mt][1] * invA),
                     (_Float16)(oA[mt][2] * invA), (_Float16)(oA[mt][3] * invA) };
        half4 hb = { (_Float16)(oB[mt][0] * invB), (_Float16)(oB[mt][1] * invB),
                     (_Float16)(oB[mt][2] * invB), (_Float16)(oB[mt][3] * invB) };
        *(half4*)(o16 + baseA + mt * 16) = ha;
        *(half4*)(o16 + baseB + mt * 16) = hb;
    }
}

// ---------------------------------------------------------------------------
// Kernel 3: y = attn16 @ Wp16^T + b_proj, fp32 out. 128x128 tile (mirror of
// qkv_gemm's proven loop: 16 MFMA/K-step/wave), grid (8, 64) = 512 blocks.
// ---------------------------------------------------------------------------
__global__ __launch_bounds__(256)
void proj_gemm(const _Float16* __restrict__ A, const _Float16* __restrict__ B,
               const float* __restrict__ bias, float* __restrict__ out)
{
    __shared__ __align__(16) _Float16 smem[16384];   // 32 KB dbuf tiles
    const int tid = threadIdx.x, lane = tid & 63, wave = tid >> 6;
    const int wm = wave & 1, wn = wave >> 1;
    const int m0 = blockIdx.y * 128, n0 = blockIdx.x * 128;
    const int l15 = lane & 15, quad = lane >> 4;

    floatx4 acc[4][4];
#pragma unroll
    for (int i = 0; i < 4; ++i)
#pragma unroll
        for (int j = 0; j < 4; ++j) acc[i][j] = (floatx4){0.f, 0.f, 0.f, 0.f};

    stage32(A, smem, m0, 0, tid);
    stage32(B, smem + 8192, n0, 0, tid);
    for (int kt = 0; kt < 32; ++kt) {
        const int cur = kt & 1;
        _Float16* Asc = smem + cur * 4096;
        _Float16* Bsc = smem + 8192 + cur * 4096;
        __syncthreads();                      // drains DMA(kt)
        if (kt < 31) {
            stage32(A, smem + (cur ^ 1) * 4096, m0, (kt + 1) * 32, tid);
            stage32(B, smem + 8192 + (cur ^ 1) * 4096, n0, (kt + 1) * 32, tid);
        }
        half8 af[4], bf[4];
#pragma unroll
        for (int mt = 0; mt < 4; ++mt) {
            int row = wm * 64 + mt * 16 + l15;
            af[mt] = *(const half8*)(Asc + row * 32 + (quad ^ (row & 3)) * 8);
        }
#pragma unroll
        for (int nt = 0; nt < 4; ++nt) {
            int row = wn * 64 + nt * 16 + l15;
            bf[nt] = *(const half8*)(Bsc + row * 32 + (quad ^ (row & 3)) * 8);
        }
#pragma unroll
        for (int mt = 0; mt < 4; ++mt)
#pragma unroll
            for (int nt = 0; nt < 4; ++nt)
                acc[mt][nt] = __builtin_amdgcn_mfma_f32_16x16x32_f16(af[mt], bf[nt], acc[mt][nt], 0, 0, 0);
    }

    const int rbase = quad << 2;
#pragma unroll
    for (int mt = 0; mt < 4; ++mt)
#pragma unroll
        for (int nt = 0; nt < 4; ++nt) {
            int gn = n0 + wn * 64 + nt * 16 + l15;
            float bb = bias[gn];
#pragma unroll
            for (int r = 0; r < 4; ++r) {
                int gm = m0 + wm * 64 + mt * 16 + rbase + r;
                out[(size_t)gm * CEMB + gn] = acc[mt][nt][r] + bb;
            }
        }
}

// ---------------------------------------------------------------------------
extern "C" void kernel_launch(void* const* d_in, const int* in_sizes, int n_in,
                              void* d_out, int out_size, void* d_ws, size_t ws_size,
                              hipStream_t stream) {
    const float* x     = (const float*)d_in[0];
    const float* Wattn = (const float*)d_in[1];
    const float* Wproj = (const float*)d_in[2];
    const float* bproj = (const float*)d_in[3];
    float* out = (float*)d_out;

    const size_t nx  = (size_t)BATCH * TSEQ * CEMB;
    const size_t nwa = (size_t)3 * CEMB * CEMB;
    const size_t nwp = (size_t)CEMB * CEMB;
    const size_t per = (size_t)BATCH * NHEAD * TSEQ * HD;

    _Float16* x16    = (_Float16*)d_ws;
    _Float16* wa16   = x16 + nx;
    _Float16* wp16   = wa16 + nwa;
    _Float16* q16    = wp16 + nwp;
    _Float16* k16    = q16 + per;
    _Float16* v16    = k16 + per;
    _Float16* attn16 = x16;   // alias: x16 fully consumed before attn writes

    const int nconv = (int)((nx + nwa + nwp) / 4);
    cvt_fp16<<<nconv / 256, 256, 0, stream>>>(x, Wattn, Wproj, x16, wa16, wp16);
    qkv_gemm<<<dim3(3 * CEMB / 128, MROWS / 128), 256, 0, stream>>>(x16, wa16, q16, k16, v16);
    attn_fwd<<<dim3(16, BATCH * NHEAD), 256, 0, stream>>>(q16, k16, v16, attn16);
    proj_gemm<<<dim3(CEMB / 128, MROWS / 128), 256, 0, stream>>>(attn16, wp16, bproj, out);
}